// Round 4
// baseline (236.019 us; speedup 1.0000x reference)
//
#include <hip/hip_runtime.h>
#include <math.h>

namespace {
constexpr int B = 16, L = 2048, H = 768, D = 64, N = 20;
constexpr int TOK = 2 * N + L;            // 2088 tokens per batch row
constexpr int ROWS = 16;                  // gather rows per block
constexpr int NQ = N * D;                 // 1280 entries per Q matrix
constexpr int NK = B * D;                 // 1024 entries per K matrix
constexpr int NQK = 2 * NQ + 2 * NK;      // 4608 dot products total
// ws layout (floats): [hsum: B*H][qk: NQK][probs_l: B*N][probs_a: B*N]
constexpr int WS_HSUM = 0;
constexpr int WS_QK = B * H;              // 12288
constexpr int WS_PL = WS_QK + NQK;        // 16896
constexpr int WS_PA = WS_PL + B * N;      // 17216
}

// ---------------------------------------------------------------------------
// Kernel 1: embedding gather -> out[:, 2N:, :], fused partial mean over L.
// grid = (B*L/ROWS) blocks x 192 threads; each thread owns 4 contiguous h.
// ---------------------------------------------------------------------------
__global__ __launch_bounds__(192) void gather_kernel(
    const int* __restrict__ ids, const float* __restrict__ wte,
    float* __restrict__ out, float* __restrict__ hsum)
{
    const int blk = blockIdx.x;                 // 0 .. B*L/ROWS-1
    const int b = blk / (L / ROWS);
    const int l0 = (blk % (L / ROWS)) * ROWS;
    const int t = threadIdx.x;                  // 0..191, h = 4t..4t+3
    float4 acc = make_float4(0.f, 0.f, 0.f, 0.f);
    float* outb = out + (size_t)b * TOK * H + (size_t)(2 * N + l0) * H;
#pragma unroll 4
    for (int r = 0; r < ROWS; ++r) {
        const int idx = ids[b * L + l0 + r];
        const float4 v = *reinterpret_cast<const float4*>(wte + (size_t)idx * H + 4 * t);
        acc.x += v.x; acc.y += v.y; acc.z += v.z; acc.w += v.w;
        *reinterpret_cast<float4*>(outb + (size_t)r * H + 4 * t) = v;
    }
    float* hs = hsum + b * H + 4 * t;
    atomicAdd(hs + 0, acc.x);
    atomicAdd(hs + 1, acc.y);
    atomicAdd(hs + 2, acc.z);
    atomicAdd(hs + 3, acc.w);
}

// ---------------------------------------------------------------------------
// Kernel 2: 4608 length-768 dot products, one wave each.
// qk layout: [Ql: N*D][Qa: N*D][Kl: B*D][Ka: B*D]
// ---------------------------------------------------------------------------
__global__ __launch_bounds__(256) void qk_kernel(
    const float* __restrict__ relevance, const float* __restrict__ prompts,
    const float* __restrict__ label_prompts,
    const float* __restrict__ aq_w, const float* __restrict__ aq_b,
    const float* __restrict__ ak_w, const float* __restrict__ ak_b,
    const float* __restrict__ lq_w, const float* __restrict__ lq_b,
    const float* __restrict__ lk_w, const float* __restrict__ lk_b,
    const float* __restrict__ hsum, float* __restrict__ qk)
{
    const int wave = (blockIdx.x * 256 + threadIdx.x) >> 6;  // global wave id
    const int lane = threadIdx.x & 63;
    if (wave >= NQK) return;

    float s = 0.f;
    float bias = 0.f;
    if (wave < NQ) {                                   // Q label
        const int n = wave / D, d = wave % D;
        const float* x = prompts + n * H;
        const float* w = lq_w + d * H;
        for (int h = lane; h < H; h += 64) s += x[h] * w[h];
        bias = lq_b[d];
    } else if (wave < 2 * NQ) {                        // Q adapter (doc)
        const int e = wave - NQ;
        const int n = e / D, d = e % D;
        const float* x = prompts + n * H;
        const float* w = aq_w + d * H;
        for (int h = lane; h < H; h += 64) s += x[h] * w[h];
        bias = aq_b[d];
    } else if (wave < 2 * NQ + NK) {                   // K label (hs_rel @ lk_w.T)
        const int e = wave - 2 * NQ;
        const int b = e / D, d = e % D;
        const float r = relevance[b];
        const float* w = lk_w + d * H;
        for (int h = lane; h < H; h += 64) {
            const float hr = (1.f - r) * label_prompts[h] + r * label_prompts[H + h];
            s += hr * w[h];
        }
        bias = lk_b[d];
    } else {                                           // K doc (hbar @ ak_w.T)
        const int e = wave - 2 * NQ - NK;
        const int b = e / D, d = e % D;
        const float* x = hsum + b * H;
        const float* w = ak_w + d * H;
        const float inv_l = 1.f / (float)L;
        for (int h = lane; h < H; h += 64) s += (x[h] * inv_l) * w[h];
        bias = ak_b[d];
    }
#pragma unroll
    for (int off = 32; off > 0; off >>= 1) s += __shfl_xor(s, off);
    if (lane == 0) qk[wave] = s + bias;
}

// ---------------------------------------------------------------------------
// Kernel 3: scores -> sigmoid probs. 2*B*N = 640 entries, 64-MAC dot each.
// ---------------------------------------------------------------------------
__global__ __launch_bounds__(64) void score_kernel(
    const float* __restrict__ qk, float* __restrict__ probs_l,
    float* __restrict__ probs_a)
{
    const int t = blockIdx.x * 64 + threadIdx.x;
    if (t >= 2 * B * N) return;
    const int seg = t / (B * N);
    const int r = t % (B * N);
    const int b = r / N, n = r % N;
    const float* Q = qk + (seg ? NQ : 0) + n * D;
    const float* K = qk + 2 * NQ + (seg ? NK : 0) + b * D;
    float s = 0.f;
#pragma unroll
    for (int d = 0; d < D; ++d) s += Q[d] * K[d];
    s *= 0.125f;                                  // 1/sqrt(64)
    const float p = 1.f / (1.f + expf(-s));
    (seg ? probs_a : probs_l)[r] = p;
}

// ---------------------------------------------------------------------------
// Kernel 4: out[b, 0:2N, :] = prompts[n,:] * prob
// grid = B*2N blocks x 192 threads (float4 per thread).
// ---------------------------------------------------------------------------
__global__ __launch_bounds__(192) void prompt_out_kernel(
    const float* __restrict__ prompts, const float* __restrict__ probs_l,
    const float* __restrict__ probs_a, float* __restrict__ out)
{
    const int blk = blockIdx.x;                  // 0 .. B*2N-1
    const int b = blk / (2 * N);
    const int sn = blk % (2 * N);
    const int seg = sn / N;
    const int n = sn % N;
    const float p = seg ? probs_a[b * N + n] : probs_l[b * N + n];
    const int t = threadIdx.x;
    float4 v = *reinterpret_cast<const float4*>(prompts + n * H + 4 * t);
    v.x *= p; v.y *= p; v.z *= p; v.w *= p;
    *reinterpret_cast<float4*>(out + (size_t)b * TOK * H + (size_t)sn * H + 4 * t) = v;
}

extern "C" void kernel_launch(void* const* d_in, const int* in_sizes, int n_in,
                              void* d_out, int out_size, void* d_ws, size_t ws_size,
                              hipStream_t stream)
{
    const float* relevance     = (const float*)d_in[0];
    const int*   input_ids     = (const int*)d_in[1];
    const float* wte_weight    = (const float*)d_in[2];
    const float* prompts       = (const float*)d_in[3];
    const float* label_prompts = (const float*)d_in[4];
    const float* aq_w = (const float*)d_in[5];
    const float* aq_b = (const float*)d_in[6];
    const float* ak_w = (const float*)d_in[7];
    const float* ak_b = (const float*)d_in[8];
    const float* lq_w = (const float*)d_in[9];
    const float* lq_b = (const float*)d_in[10];
    const float* lk_w = (const float*)d_in[11];
    const float* lk_b = (const float*)d_in[12];
    float* out = (float*)d_out;

    float* ws      = (float*)d_ws;
    float* hsum    = ws + WS_HSUM;
    float* qk      = ws + WS_QK;
    float* probs_l = ws + WS_PL;
    float* probs_a = ws + WS_PA;

    // hbar accumulator must start at zero every call (ws is poisoned 0xAA).
    hipMemsetAsync(hsum, 0, B * H * sizeof(float), stream);

    gather_kernel<<<B * L / ROWS, 192, 0, stream>>>(input_ids, wte_weight, out, hsum);
    qk_kernel<<<(NQK * 64 + 255) / 256, 256, 0, stream>>>(
        relevance, prompts, label_prompts, aq_w, aq_b, ak_w, ak_b,
        lq_w, lq_b, lk_w, lk_b, hsum, qk);
    score_kernel<<<(2 * B * N + 63) / 64, 64, 0, stream>>>(qk, probs_l, probs_a);
    prompt_out_kernel<<<B * 2 * N, 192, 0, stream>>>(prompts, probs_l, probs_a, out);
}

// Round 5
// 220.330 us; speedup vs baseline: 1.0712x; 1.0712x over previous
//
#include <hip/hip_runtime.h>
#include <math.h>

namespace {
constexpr int B = 16, L = 2048, H = 768, D = 64, N = 20;
constexpr int TOK = 2 * N + L;            // 2088 tokens per batch row
constexpr int ROWS = 16;                  // gather rows per block
constexpr int BLK_PER_B = L / ROWS;       // 128 blocks per batch row
constexpr int NBLK = B * BLK_PER_B;       // 2048 gather blocks
constexpr int NQ = N * D;                 // 1280 entries per Q matrix
constexpr int NK = B * D;                 // 1024 entries per K matrix
constexpr int NQK = 2 * NQ + 2 * NK;      // 4608 dot products total
// ws layout (floats):
// [partial: NBLK*H][hsum: B*H][qk: NQK][probs_l: B*N][probs_a: B*N]
constexpr int WS_PART = 0;
constexpr int WS_HSUM = NBLK * H;             // 1,572,864
constexpr int WS_QK   = WS_HSUM + B * H;      // +12,288
constexpr int WS_PL   = WS_QK + NQK;          // +4,608
constexpr int WS_PA   = WS_PL + B * N;        // +320
}

// ---------------------------------------------------------------------------
// Kernel 1: embedding gather -> out[:, 2N:, :]; per-block partial column sums
// written to `partial` with plain coalesced stores (NO atomics — the Round-4
// profile showed +25 MB of RMW write traffic and a same-line atomic convoy:
// 2048 same-line atomics per 64B line across 8 XCDs).
// grid = NBLK x 192 threads; thread t owns h = 4t..4t+3.
// ---------------------------------------------------------------------------
__global__ __launch_bounds__(192) void gather_kernel(
    const int* __restrict__ ids, const float* __restrict__ wte,
    float* __restrict__ out, float* __restrict__ partial)
{
    const int blk = blockIdx.x;                 // b * BLK_PER_B + lblk
    const int b = blk / BLK_PER_B;
    const int l0 = (blk % BLK_PER_B) * ROWS;
    const int t = threadIdx.x;                  // 0..191
    float4 acc = make_float4(0.f, 0.f, 0.f, 0.f);
    float* outb = out + (size_t)b * TOK * H + (size_t)(2 * N + l0) * H;
#pragma unroll 4
    for (int r = 0; r < ROWS; ++r) {
        const int idx = ids[b * L + l0 + r];
        const float4 v = *reinterpret_cast<const float4*>(wte + (size_t)idx * H + 4 * t);
        acc.x += v.x; acc.y += v.y; acc.z += v.z; acc.w += v.w;
        *reinterpret_cast<float4*>(outb + (size_t)r * H + 4 * t) = v;
    }
    *reinterpret_cast<float4*>(partial + (size_t)blk * H + 4 * t) = acc;
}

// ---------------------------------------------------------------------------
// Kernel 2: hsum[b][h] = sum over 128 per-block partials. 12288 threads,
// consecutive threads read consecutive h (coalesced, stride-H walk over k).
// ---------------------------------------------------------------------------
__global__ __launch_bounds__(256) void reduce_kernel(
    const float* __restrict__ partial, float* __restrict__ hsum)
{
    const int g = blockIdx.x * 256 + threadIdx.x;   // 0 .. B*H-1
    if (g >= B * H) return;
    const int b = g / H, h = g % H;
    const float* p = partial + (size_t)b * BLK_PER_B * H + h;
    float s = 0.f;
#pragma unroll 8
    for (int k = 0; k < BLK_PER_B; ++k) s += p[(size_t)k * H];
    hsum[g] = s;
}

// ---------------------------------------------------------------------------
// Kernel 3: 4608 length-768 dot products, one wave each, float4 lanes.
// qk layout: [Ql: N*D][Qa: N*D][Kl: B*D][Ka: B*D]
// ---------------------------------------------------------------------------
__global__ __launch_bounds__(256) void qk_kernel(
    const float* __restrict__ relevance, const float* __restrict__ prompts,
    const float* __restrict__ label_prompts,
    const float* __restrict__ aq_w, const float* __restrict__ aq_b,
    const float* __restrict__ ak_w, const float* __restrict__ ak_b,
    const float* __restrict__ lq_w, const float* __restrict__ lq_b,
    const float* __restrict__ lk_w, const float* __restrict__ lk_b,
    const float* __restrict__ hsum, float* __restrict__ qk)
{
    const int wave = (blockIdx.x * 256 + threadIdx.x) >> 6;  // global wave id
    const int lane = threadIdx.x & 63;
    if (wave >= NQK) return;

    float s = 0.f;
    float bias = 0.f;
    if (wave < 2 * NQ) {                               // Q label / Q doc
        const int e = wave < NQ ? wave : wave - NQ;
        const int n = e / D, d = e % D;
        const float4* x = reinterpret_cast<const float4*>(prompts + n * H);
        const float4* w = reinterpret_cast<const float4*>(
            (wave < NQ ? lq_w : aq_w) + d * H);
#pragma unroll
        for (int k = lane; k < H / 4; k += 64) {
            const float4 a = x[k], c = w[k];
            s += a.x * c.x + a.y * c.y + a.z * c.z + a.w * c.w;
        }
        bias = (wave < NQ ? lq_b : aq_b)[d];
    } else if (wave < 2 * NQ + NK) {                   // K label (hs_rel @ lk_w.T)
        const int e = wave - 2 * NQ;
        const int b = e / D, d = e % D;
        const float r = relevance[b];
        const float4* p0 = reinterpret_cast<const float4*>(label_prompts);
        const float4* p1 = reinterpret_cast<const float4*>(label_prompts + H);
        const float4* w = reinterpret_cast<const float4*>(lk_w + d * H);
#pragma unroll
        for (int k = lane; k < H / 4; k += 64) {
            const float4 a = p0[k], bb = p1[k], c = w[k];
            s += ((1.f - r) * a.x + r * bb.x) * c.x
               + ((1.f - r) * a.y + r * bb.y) * c.y
               + ((1.f - r) * a.z + r * bb.z) * c.z
               + ((1.f - r) * a.w + r * bb.w) * c.w;
        }
        bias = lk_b[d];
    } else {                                           // K doc (hbar @ ak_w.T)
        const int e = wave - 2 * NQ - NK;
        const int b = e / D, d = e % D;
        const float4* x = reinterpret_cast<const float4*>(hsum + b * H);
        const float4* w = reinterpret_cast<const float4*>(ak_w + d * H);
        const float inv_l = 1.f / (float)L;
#pragma unroll
        for (int k = lane; k < H / 4; k += 64) {
            const float4 a = x[k], c = w[k];
            s += inv_l * (a.x * c.x + a.y * c.y + a.z * c.z + a.w * c.w);
        }
        bias = ak_b[d];
    }
#pragma unroll
    for (int off = 32; off > 0; off >>= 1) s += __shfl_xor(s, off);
    if (lane == 0) qk[wave] = s + bias;
}

// ---------------------------------------------------------------------------
// Kernel 4: scores -> sigmoid probs. 2*B*N = 640 entries, 64-MAC dot each.
// ---------------------------------------------------------------------------
__global__ __launch_bounds__(64) void score_kernel(
    const float* __restrict__ qk, float* __restrict__ probs_l,
    float* __restrict__ probs_a)
{
    const int t = blockIdx.x * 64 + threadIdx.x;
    if (t >= 2 * B * N) return;
    const int seg = t / (B * N);
    const int r = t % (B * N);
    const int b = r / N, n = r % N;
    const float* Q = qk + (seg ? NQ : 0) + n * D;
    const float* K = qk + 2 * NQ + (seg ? NK : 0) + b * D;
    float s = 0.f;
#pragma unroll
    for (int d = 0; d < D; ++d) s += Q[d] * K[d];
    s *= 0.125f;                                  // 1/sqrt(64)
    const float p = 1.f / (1.f + expf(-s));
    (seg ? probs_a : probs_l)[r] = p;
}

// ---------------------------------------------------------------------------
// Kernel 5: out[b, 0:2N, :] = prompts[n,:] * prob
// grid = B*2N blocks x 192 threads (float4 per thread).
// ---------------------------------------------------------------------------
__global__ __launch_bounds__(192) void prompt_out_kernel(
    const float* __restrict__ prompts, const float* __restrict__ probs_l,
    const float* __restrict__ probs_a, float* __restrict__ out)
{
    const int blk = blockIdx.x;                  // 0 .. B*2N-1
    const int b = blk / (2 * N);
    const int sn = blk % (2 * N);
    const int seg = sn / N;
    const int n = sn % N;
    const float p = seg ? probs_a[b * N + n] : probs_l[b * N + n];
    const int t = threadIdx.x;
    float4 v = *reinterpret_cast<const float4*>(prompts + n * H + 4 * t);
    v.x *= p; v.y *= p; v.z *= p; v.w *= p;
    *reinterpret_cast<float4*>(out + (size_t)b * TOK * H + (size_t)sn * H + 4 * t) = v;
}

extern "C" void kernel_launch(void* const* d_in, const int* in_sizes, int n_in,
                              void* d_out, int out_size, void* d_ws, size_t ws_size,
                              hipStream_t stream)
{
    const float* relevance     = (const float*)d_in[0];
    const int*   input_ids     = (const int*)d_in[1];
    const float* wte_weight    = (const float*)d_in[2];
    const float* prompts       = (const float*)d_in[3];
    const float* label_prompts = (const float*)d_in[4];
    const float* aq_w = (const float*)d_in[5];
    const float* aq_b = (const float*)d_in[6];
    const float* ak_w = (const float*)d_in[7];
    const float* ak_b = (const float*)d_in[8];
    const float* lq_w = (const float*)d_in[9];
    const float* lq_b = (const float*)d_in[10];
    const float* lk_w = (const float*)d_in[11];
    const float* lk_b = (const float*)d_in[12];
    float* out = (float*)d_out;

    float* ws      = (float*)d_ws;
    float* partial = ws + WS_PART;
    float* hsum    = ws + WS_HSUM;
    float* qk      = ws + WS_QK;
    float* probs_l = ws + WS_PL;
    float* probs_a = ws + WS_PA;

    gather_kernel<<<NBLK, 192, 0, stream>>>(input_ids, wte_weight, out, partial);
    reduce_kernel<<<(B * H + 255) / 256, 256, 0, stream>>>(partial, hsum);
    qk_kernel<<<(NQK * 64 + 255) / 256, 256, 0, stream>>>(
        relevance, prompts, label_prompts, aq_w, aq_b, ak_w, ak_b,
        lq_w, lq_b, lk_w, lk_b, hsum, qk);
    score_kernel<<<(2 * B * N + 63) / 64, 64, 0, stream>>>(qk, probs_l, probs_a);
    prompt_out_kernel<<<B * 2 * N, 192, 0, stream>>>(prompts, probs_l, probs_a, out);
}

// Round 6
// 215.358 us; speedup vs baseline: 1.0959x; 1.0231x over previous
//
#include <hip/hip_runtime.h>
#include <math.h>

namespace {
constexpr int B = 16, L = 2048, H = 768, D = 64, N = 20;
constexpr int TOK = 2 * N + L;            // 2088 tokens per batch row
constexpr int ROWS = 16;                  // gather rows per block
constexpr int BLK_PER_B = L / ROWS;       // 128 blocks per batch row
constexpr int NBLK = B * BLK_PER_B;       // 2048 gather blocks
constexpr int NQ = N * D;                 // 1280 entries per Q matrix
constexpr int NK = B * D;                 // 1024 entries per K matrix
constexpr int NQK = 2 * NQ + 2 * NK;      // 4608 dot products total
// ws layout (floats):
// [partial: NBLK*H][hsum: B*H][qk: NQK]
constexpr int WS_PART = 0;
constexpr int WS_HSUM = NBLK * H;             // 1,572,864
constexpr int WS_QK   = WS_HSUM + B * H;      // +12,288
typedef float f32x4 __attribute__((ext_vector_type(4)));
}

// ---------------------------------------------------------------------------
// Kernel 1: embedding gather -> out[:, 2N:, :]; per-block partial column sums
// to `partial` (plain stores — R4 profile showed the atomic version cost
// +25 MB RMW traffic and a same-line convoy; partial-write version is faster).
// This round: FULL 16-deep unroll (16 row loads in flight per thread) and
// NON-TEMPORAL stores for the write-once output stream so it doesn't evict
// the L2/L3-resident wte rows (FETCH_SIZE=47.5 MB << 100.7 MB logical shows
// the cache is absorbing most re-reads — protect that).
// grid = NBLK x 192 threads; thread t owns h = 4t..4t+3.
// ---------------------------------------------------------------------------
__global__ __launch_bounds__(192) void gather_kernel(
    const int* __restrict__ ids, const float* __restrict__ wte,
    float* __restrict__ out, float* __restrict__ partial)
{
    const int blk = blockIdx.x;                 // b * BLK_PER_B + lblk
    const int b = blk / BLK_PER_B;
    const int l0 = (blk % BLK_PER_B) * ROWS;
    const int t = threadIdx.x;                  // 0..191
    f32x4 acc = {0.f, 0.f, 0.f, 0.f};
    float* outb = out + (size_t)b * TOK * H + (size_t)(2 * N + l0) * H;
#pragma unroll
    for (int r = 0; r < ROWS; ++r) {
        const int idx = ids[b * L + l0 + r];
        const f32x4 v = *reinterpret_cast<const f32x4*>(wte + (size_t)idx * H + 4 * t);
        acc += v;
        __builtin_nontemporal_store(
            v, reinterpret_cast<f32x4*>(outb + (size_t)r * H + 4 * t));
    }
    *reinterpret_cast<f32x4*>(partial + (size_t)blk * H + 4 * t) = acc;
}

// ---------------------------------------------------------------------------
// Kernel 2: hsum[b][h] = sum over 128 per-block partials. 12288 threads,
// consecutive threads read consecutive h (coalesced at each k step).
// ---------------------------------------------------------------------------
__global__ __launch_bounds__(256) void reduce_kernel(
    const float* __restrict__ partial, float* __restrict__ hsum)
{
    const int g = blockIdx.x * 256 + threadIdx.x;   // 0 .. B*H-1
    if (g >= B * H) return;
    const int b = g / H, h = g % H;
    const float* p = partial + (size_t)b * BLK_PER_B * H + h;
    float s = 0.f;
#pragma unroll 8
    for (int k = 0; k < BLK_PER_B; ++k) s += p[(size_t)k * H];
    hsum[g] = s;
}

// ---------------------------------------------------------------------------
// Kernel 3: 4608 length-768 dot products, one wave each, float4 lanes.
// qk layout: [Ql: N*D][Qa: N*D][Kl: B*D][Ka: B*D]
// ---------------------------------------------------------------------------
__global__ __launch_bounds__(256) void qk_kernel(
    const float* __restrict__ relevance, const float* __restrict__ prompts,
    const float* __restrict__ label_prompts,
    const float* __restrict__ aq_w, const float* __restrict__ aq_b,
    const float* __restrict__ ak_w, const float* __restrict__ ak_b,
    const float* __restrict__ lq_w, const float* __restrict__ lq_b,
    const float* __restrict__ lk_w, const float* __restrict__ lk_b,
    const float* __restrict__ hsum, float* __restrict__ qk)
{
    const int wave = (blockIdx.x * 256 + threadIdx.x) >> 6;  // global wave id
    const int lane = threadIdx.x & 63;
    if (wave >= NQK) return;

    float s = 0.f;
    float bias = 0.f;
    if (wave < 2 * NQ) {                               // Q label / Q doc
        const int e = wave < NQ ? wave : wave - NQ;
        const int n = e / D, d = e % D;
        const float4* x = reinterpret_cast<const float4*>(prompts + n * H);
        const float4* w = reinterpret_cast<const float4*>(
            (wave < NQ ? lq_w : aq_w) + d * H);
#pragma unroll
        for (int k = lane; k < H / 4; k += 64) {
            const float4 a = x[k], c = w[k];
            s += a.x * c.x + a.y * c.y + a.z * c.z + a.w * c.w;
        }
        bias = (wave < NQ ? lq_b : aq_b)[d];
    } else if (wave < 2 * NQ + NK) {                   // K label (hs_rel @ lk_w.T)
        const int e = wave - 2 * NQ;
        const int b = e / D, d = e % D;
        const float r = relevance[b];
        const float4* p0 = reinterpret_cast<const float4*>(label_prompts);
        const float4* p1 = reinterpret_cast<const float4*>(label_prompts + H);
        const float4* w = reinterpret_cast<const float4*>(lk_w + d * H);
#pragma unroll
        for (int k = lane; k < H / 4; k += 64) {
            const float4 a = p0[k], bb = p1[k], c = w[k];
            s += ((1.f - r) * a.x + r * bb.x) * c.x
               + ((1.f - r) * a.y + r * bb.y) * c.y
               + ((1.f - r) * a.z + r * bb.z) * c.z
               + ((1.f - r) * a.w + r * bb.w) * c.w;
        }
        bias = lk_b[d];
    } else {                                           // K doc (hbar @ ak_w.T)
        const int e = wave - 2 * NQ - NK;
        const int b = e / D, d = e % D;
        const float4* x = reinterpret_cast<const float4*>(hsum + b * H);
        const float4* w = reinterpret_cast<const float4*>(ak_w + d * H);
        const float inv_l = 1.f / (float)L;
#pragma unroll
        for (int k = lane; k < H / 4; k += 64) {
            const float4 a = x[k], c = w[k];
            s += inv_l * (a.x * c.x + a.y * c.y + a.z * c.z + a.w * c.w);
        }
        bias = ak_b[d];
    }
#pragma unroll
    for (int off = 32; off > 0; off >>= 1) s += __shfl_xor(s, off);
    if (lane == 0) qk[wave] = s + bias;
}

// ---------------------------------------------------------------------------
// Kernel 4 (fused score + prompt write): out[b, 0:2N, :] = prompts[n,:] *
// sigmoid(dot(Q[n], K[b]) / 8). Wave 0 computes the 64-MAC dot via butterfly,
// broadcasts through LDS; all 192 threads then write one float4.
// grid = B*2N blocks x 192 threads.
// ---------------------------------------------------------------------------
__global__ __launch_bounds__(192) void prompt_out_kernel(
    const float* __restrict__ prompts, const float* __restrict__ qk,
    float* __restrict__ out)
{
    __shared__ float sp;
    const int blk = blockIdx.x;                  // 0 .. B*2N-1
    const int b = blk / (2 * N);
    const int sn = blk % (2 * N);
    const int seg = sn / N;                      // 0 = label, 1 = doc
    const int n = sn % N;
    const int t = threadIdx.x;
    if (t < 64) {
        const float q = qk[(seg ? NQ : 0) + n * D + t];
        const float k = qk[2 * NQ + (seg ? NK : 0) + b * D + t];
        float s = q * k;
#pragma unroll
        for (int off = 32; off > 0; off >>= 1) s += __shfl_xor(s, off);
        if (t == 0) sp = 1.f / (1.f + expf(-0.125f * s));
    }
    __syncthreads();
    const float p = sp;
    f32x4 v = *reinterpret_cast<const f32x4*>(prompts + n * H + 4 * t);
    v *= p;
    __builtin_nontemporal_store(
        v, reinterpret_cast<f32x4*>(out + (size_t)b * TOK * H + (size_t)sn * H + 4 * t));
}

extern "C" void kernel_launch(void* const* d_in, const int* in_sizes, int n_in,
                              void* d_out, int out_size, void* d_ws, size_t ws_size,
                              hipStream_t stream)
{
    const float* relevance     = (const float*)d_in[0];
    const int*   input_ids     = (const int*)d_in[1];
    const float* wte_weight    = (const float*)d_in[2];
    const float* prompts       = (const float*)d_in[3];
    const float* label_prompts = (const float*)d_in[4];
    const float* aq_w = (const float*)d_in[5];
    const float* aq_b = (const float*)d_in[6];
    const float* ak_w = (const float*)d_in[7];
    const float* ak_b = (const float*)d_in[8];
    const float* lq_w = (const float*)d_in[9];
    const float* lq_b = (const float*)d_in[10];
    const float* lk_w = (const float*)d_in[11];
    const float* lk_b = (const float*)d_in[12];
    float* out = (float*)d_out;

    float* ws      = (float*)d_ws;
    float* partial = ws + WS_PART;
    float* hsum    = ws + WS_HSUM;
    float* qk      = ws + WS_QK;

    gather_kernel<<<NBLK, 192, 0, stream>>>(input_ids, wte_weight, out, partial);
    reduce_kernel<<<(B * H + 255) / 256, 256, 0, stream>>>(partial, hsum);
    qk_kernel<<<(NQK * 64 + 255) / 256, 256, 0, stream>>>(
        relevance, prompts, label_prompts, aq_w, aq_b, ak_w, ak_b,
        lq_w, lq_b, lk_w, lk_b, hsum, qk);
    prompt_out_kernel<<<B * 2 * N, 192, 0, stream>>>(prompts, qk, out);
}